// Round 4
// baseline (137.466 us; speedup 1.0000x reference)
//
#include <hip/hip_runtime.h>
#include <hip/hip_bf16.h>

// NRI Encoder, MI355X. Fully factorized + pi-permuted-weight register chain.
// Key trick: MFMA D-layout -> next B-frag layout is a fixed per-lane feature
// permutation pi; pre-permuting weight ROWS by pi in prepack makes the
// accumulator registers directly usable as the next GEMM's B operand.
// Edge kernel: 1 wave/block, all-stage weights register-resident (~400 VGPR),
// 16 tiles per wave (quarter scheduling), zero LDS, zero barriers.

#define DI __device__ __forceinline__

typedef short bf16x8 __attribute__((ext_vector_type(8)));
typedef float f32x4 __attribute__((ext_vector_type(4)));
typedef unsigned short u16;

static constexpr int NN = 64, NE = 4032, H = 128;

DI u16 f2bf(float f) {
  union { float f; unsigned u; } v; v.f = f;
  unsigned u = v.u;
  return (u16)((u + 0x7fffu + ((u >> 16) & 1u)) >> 16);
}
DI unsigned pk2(float a, float b) {
  union { __hip_bfloat162 h; unsigned u; } c;
  c.h = __float22bfloat162_rn(float2{a, b});
  return c.u;
}
DI f32x4 mf(bf16x8 a, bf16x8 b, f32x4 c) {
  return __builtin_amdgcn_mfma_f32_16x16x32_bf16(a, b, c, 0, 0, 0);
}
DI bf16x8 ldfrag(const u16* __restrict__ p, int idx, int l) {
  return *reinterpret_cast<const bf16x8*>(p + (idx * 64 + l) * 8);
}

// ---- prepack: all weights -> MFMA A-frag-of-W^T order; pi row-permutation
// for chained stages; also computes folded bias vectors c2, c4.
// frag layout: dst[(frag*64+lane)*8+jj] = W[roff + row(kt,h,jj)][ct*16+(lane&15)]
//   natural: row = kt*32 + h*8 + jj         (stage inputs built from scratch)
//   pi:      row = kt*32 + (jj>>2)*16 + h*4 + (jj&3)   (chained stages)
__global__ __launch_bounds__(64) void prepack_kernel(
    const float* __restrict__ w1a, const float* __restrict__ w1b,
    const float* __restrict__ w2a, const float* __restrict__ w2b,
    const float* __restrict__ w3a, const float* __restrict__ w3b,
    const float* __restrict__ w4a, const float* __restrict__ w4b,
    const float* __restrict__ wout,
    const float* __restrict__ b2b, const float* __restrict__ b4b,
    const float* __restrict__ bout,
    u16* __restrict__ pk, float* __restrict__ c2, float* __restrict__ c4) {
  int seg = blockIdx.y, f = blockIdx.x, l = threadIdx.x;
  if (seg == 12) {  // folded biases
    if (f < 2) {
      int o = f * 64 + l;
      float s = 0.f;
      for (int k = 0; k < 128; k++) s += b2b[k] * w4a[(256 + k) * 128 + o];
      c2[o] = s;
    } else if (f == 2 && l < 16) {
      float s = bout[l];
      for (int k = 0; k < 128; k++) s += b4b[k] * wout[k * 16 + l];
      c4[l] = s;
    }
    return;
  }
  const float* src; int foff, nfrag, nct, roff, ld, pi;
  switch (seg) {
    case 0:  src = w1a;  foff = 0;   nfrag = 16; nct = 8; roff = 0;   ld = 128; pi = 0; break;
    case 1:  src = w1b;  foff = 16;  nfrag = 32; nct = 8; roff = 0;   ld = 128; pi = 1; break;
    case 2:  src = w2a;  foff = 48;  nfrag = 32; nct = 8; roff = 0;   ld = 128; pi = 1; break;
    case 3:  src = w2a;  foff = 80;  nfrag = 32; nct = 8; roff = 128; ld = 128; pi = 1; break;
    case 4:  src = w2b;  foff = 112; nfrag = 32; nct = 8; roff = 0;   ld = 128; pi = 0; break;
    case 5:  src = w3a;  foff = 144; nfrag = 32; nct = 8; roff = 0;   ld = 128; pi = 1; break;
    case 6:  src = w3b;  foff = 176; nfrag = 32; nct = 8; roff = 0;   ld = 128; pi = 1; break;
    case 7:  src = w4a;  foff = 208; nfrag = 32; nct = 8; roff = 0;   ld = 128; pi = 1; break;
    case 8:  src = w4a;  foff = 240; nfrag = 32; nct = 8; roff = 128; ld = 128; pi = 1; break;
    case 9:  src = w4a;  foff = 272; nfrag = 32; nct = 8; roff = 256; ld = 128; pi = 1; break;
    case 10: src = w4b;  foff = 304; nfrag = 32; nct = 8; roff = 0;   ld = 128; pi = 1; break;
    default: src = wout; foff = 336; nfrag = 4;  nct = 1; roff = 0;   ld = 16;  pi = 1; break;
  }
  if (f >= nfrag) return;
  int kt = f / nct, ct = f % nct, h = l >> 4, mm = l & 15;
  union { u16 u[8]; uint4 q; } o;
#pragma unroll
  for (int jj = 0; jj < 8; jj++) {
    int row = pi ? (kt * 32 + (jj >> 2) * 16 + h * 4 + (jj & 3))
                 : (kt * 32 + h * 8 + jj);
    o.u[jj] = f2bf(src[(roff + row) * ld + ct * 16 + mm]);
  }
  *reinterpret_cast<uint4*>(pk + ((foff + f) * 64 + l) * 8) = o.q;
}

// ---- node kernel: x -> h1 -> h -> sproj, rproj. 256 blocks x 1 wave,
// per-stage weight reload into double-buffered register sets.
__global__ __launch_bounds__(64) void node_kernel(
    const float* __restrict__ x, const u16* __restrict__ pk,
    const float* __restrict__ b1a, const float* __restrict__ b1b,
    const float* __restrict__ b2a,
    float* __restrict__ sproj, float* __restrict__ rproj) {
  int blk = blockIdx.x, b = blk >> 2, nq = blk & 3;
  int l = threadIdx.x, m = l & 15, h = l >> 4;
  int node = nq * 16 + m;
  const f32x4 Z = {0.f, 0.f, 0.f, 0.f};
  bf16x8 wA[32], wB[32];
#pragma unroll
  for (int i = 0; i < 16; i++) wA[i] = ldfrag(pk, i, l);          // w1a
#pragma unroll
  for (int i = 0; i < 32; i++) wB[i] = ldfrag(pk + 16 * 512, i, l);  // w1b (pi)
  f32x4 acc[8]; bf16x8 ef[4];
  const float* xb = x + (b * NN + node) * 64;
#pragma unroll
  for (int kt = 0; kt < 2; kt++) {  // stage 1, K=64
    f32x4 a0 = *(const f32x4*)(xb + kt * 32 + h * 8);
    f32x4 a1 = *(const f32x4*)(xb + kt * 32 + h * 8 + 4);
    union { unsigned u[4]; bf16x8 v; } t;
    t.u[0] = pk2(a0[0], a0[1]); t.u[1] = pk2(a0[2], a0[3]);
    t.u[2] = pk2(a1[0], a1[1]); t.u[3] = pk2(a1[2], a1[3]);
#pragma unroll
    for (int ft = 0; ft < 8; ft++)
      acc[ft] = mf(wA[kt * 8 + ft], t.v, kt == 0 ? Z : acc[ft]);
  }
#pragma unroll
  for (int k2 = 0; k2 < 4; k2++) {  // +b1a, relu -> ef
    f32x4 bA = *(const f32x4*)(b1a + (2 * k2) * 16 + h * 4);
    f32x4 bB = *(const f32x4*)(b1a + (2 * k2 + 1) * 16 + h * 4);
    f32x4 a0 = acc[2 * k2], a1 = acc[2 * k2 + 1];
    union { unsigned u[4]; bf16x8 v; } t;
    t.u[0] = pk2(fmaxf(a0[0] + bA[0], 0.f), fmaxf(a0[1] + bA[1], 0.f));
    t.u[1] = pk2(fmaxf(a0[2] + bA[2], 0.f), fmaxf(a0[3] + bA[3], 0.f));
    t.u[2] = pk2(fmaxf(a1[0] + bB[0], 0.f), fmaxf(a1[1] + bB[1], 0.f));
    t.u[3] = pk2(fmaxf(a1[2] + bB[2], 0.f), fmaxf(a1[3] + bB[3], 0.f));
    ef[k2] = t.v;
  }
#pragma unroll
  for (int i = 0; i < 32; i++) wA[i] = ldfrag(pk + 48 * 512, i, l);  // w2a_s (pi)
#pragma unroll
  for (int kt = 0; kt < 4; kt++)  // stage 2 (wB = w1b)
#pragma unroll
    for (int ft = 0; ft < 8; ft++)
      acc[ft] = mf(wB[kt * 8 + ft], ef[kt], kt == 0 ? Z : acc[ft]);
  bf16x8 efh[4];
#pragma unroll
  for (int k2 = 0; k2 < 4; k2++) {  // +b1b -> efh
    f32x4 bA = *(const f32x4*)(b1b + (2 * k2) * 16 + h * 4);
    f32x4 bB = *(const f32x4*)(b1b + (2 * k2 + 1) * 16 + h * 4);
    f32x4 a0 = acc[2 * k2], a1 = acc[2 * k2 + 1];
    union { unsigned u[4]; bf16x8 v; } t;
    t.u[0] = pk2(a0[0] + bA[0], a0[1] + bA[1]);
    t.u[1] = pk2(a0[2] + bA[2], a0[3] + bA[3]);
    t.u[2] = pk2(a1[0] + bB[0], a1[1] + bB[1]);
    t.u[3] = pk2(a1[2] + bB[2], a1[3] + bB[3]);
    efh[k2] = t.v;
  }
#pragma unroll
  for (int i = 0; i < 32; i++) wB[i] = ldfrag(pk + 80 * 512, i, l);  // w2a_r (pi)
#pragma unroll
  for (int kt = 0; kt < 4; kt++)  // stage 3: sproj (wA)
#pragma unroll
    for (int ft = 0; ft < 8; ft++)
      acc[ft] = mf(wA[kt * 8 + ft], efh[kt], kt == 0 ? Z : acc[ft]);
  float* spo = sproj + (b * NN + node) * H;
#pragma unroll
  for (int ft = 0; ft < 8; ft++)
    *reinterpret_cast<f32x4*>(spo + ft * 16 + h * 4) = acc[ft];
#pragma unroll
  for (int kt = 0; kt < 4; kt++)  // stage 4: rproj (wB)
#pragma unroll
    for (int ft = 0; ft < 8; ft++)
      acc[ft] = mf(wB[kt * 8 + ft], efh[kt], kt == 0 ? Z : acc[ft]);
  float* rpo = rproj + (b * NN + node) * H;
#pragma unroll
  for (int ft = 0; ft < 8; ft++) {
    f32x4 bb = *(const f32x4*)(b2a + ft * 16 + h * 4);
    f32x4 o = acc[ft];
    o[0] += bb[0]; o[1] += bb[1]; o[2] += bb[2]; o[3] += bb[3];
    *reinterpret_cast<f32x4*>(rpo + ft * 16 + h * 4) = o;
  }
}

// ---- agg kernel: relu-sum over senders (4 waves) + chain to s4, r4 (wave 0)
__global__ __launch_bounds__(256) void agg_kernel(
    const float* __restrict__ sproj, const float* __restrict__ rproj,
    const u16* __restrict__ pk,
    const float* __restrict__ b2b, const float* __restrict__ b3a,
    const float* __restrict__ b3b, const float* __restrict__ b4a,
    const float* __restrict__ c2,
    float* __restrict__ s4, float* __restrict__ r4) {
  __shared__ float lred[3][32][65];
  int blk = blockIdx.x, b = blk >> 2, jq = blk & 3;
  int tid = threadIdx.x, l = tid & 63, w = tid >> 6, m = l & 15, h = l >> 4;
  int j = jq * 16 + m;
  const float* rpb = rproj + (b * NN + j) * H;
  f32x4 rpv[8], accS[8];
#pragma unroll
  for (int k = 0; k < 8; k++) {
    rpv[k] = *(const f32x4*)(rpb + (k >> 1) * 32 + h * 8 + (k & 1) * 4);
    accS[k] = f32x4{0.f, 0.f, 0.f, 0.f};
  }
  const float* spb = sproj + b * NN * H;
  for (int i = w * 16; i < w * 16 + 16; i++) {
    const float* sp = spb + i * H;
#pragma unroll
    for (int k = 0; k < 8; k++) {
      f32x4 s = *(const f32x4*)(sp + (k >> 1) * 32 + h * 8 + (k & 1) * 4);
      f32x4 t = s + rpv[k];
      t[0] = fmaxf(t[0], 0.f); t[1] = fmaxf(t[1], 0.f);
      t[2] = fmaxf(t[2], 0.f); t[3] = fmaxf(t[3], 0.f);
      accS[k] += t;
    }
  }
  if (w == jq) {  // subtract self-loop i==j
    const float* sp = spb + j * H;
#pragma unroll
    for (int k = 0; k < 8; k++) {
      f32x4 s = *(const f32x4*)(sp + (k >> 1) * 32 + h * 8 + (k & 1) * 4);
      f32x4 t = s + rpv[k];
      accS[k][0] -= fmaxf(t[0], 0.f); accS[k][1] -= fmaxf(t[1], 0.f);
      accS[k][2] -= fmaxf(t[2], 0.f); accS[k][3] -= fmaxf(t[3], 0.f);
    }
  }
  if (w > 0) {
#pragma unroll
    for (int k = 0; k < 8; k++)
#pragma unroll
      for (int qq = 0; qq < 4; qq++) lred[w - 1][k * 4 + qq][l] = accS[k][qq];
  }
  __syncthreads();
  if (w != 0) return;
#pragma unroll
  for (int ww = 0; ww < 3; ww++)
#pragma unroll
    for (int k = 0; k < 8; k++)
#pragma unroll
      for (int qq = 0; qq < 4; qq++) accS[k][qq] += lred[ww][k * 4 + qq][l];

  const f32x4 Z = {0.f, 0.f, 0.f, 0.f};
  bf16x8 tb[4];
#pragma unroll
  for (int k2 = 0; k2 < 4; k2++) {
    f32x4 a0 = accS[2 * k2], a1 = accS[2 * k2 + 1];
    union { unsigned u[4]; bf16x8 v; } t;
    t.u[0] = pk2(a0[0], a0[1]); t.u[1] = pk2(a0[2], a0[3]);
    t.u[2] = pk2(a1[0], a1[1]); t.u[3] = pk2(a1[2], a1[3]);
    tb[k2] = t.v;
  }
  bf16x8 wA[32], wB[32]; f32x4 acc[8]; bf16x8 ef[4], efn[4];
#pragma unroll
  for (int i = 0; i < 32; i++) wA[i] = ldfrag(pk + 112 * 512, i, l);  // w2b nat
#pragma unroll
  for (int i = 0; i < 32; i++) wB[i] = ldfrag(pk + 144 * 512, i, l);  // w3a pi
#pragma unroll
  for (int kt = 0; kt < 4; kt++)
#pragma unroll
    for (int ft = 0; ft < 8; ft++)
      acc[ft] = mf(wA[kt * 8 + ft], tb[kt], kt == 0 ? Z : acc[ft]);
  const float inv = 1.0f / (63.0f + 1e-6f);
  const float binv = 63.0f * inv;
#pragma unroll
  for (int k2 = 0; k2 < 4; k2++) {  // agg = (sum@w2b + 63 b2b)/63.000001
    f32x4 bA = *(const f32x4*)(b2b + (2 * k2) * 16 + h * 4);
    f32x4 bB = *(const f32x4*)(b2b + (2 * k2 + 1) * 16 + h * 4);
    f32x4 a0 = acc[2 * k2], a1 = acc[2 * k2 + 1];
    union { unsigned u[4]; bf16x8 v; } t;
    t.u[0] = pk2(a0[0] * inv + bA[0] * binv, a0[1] * inv + bA[1] * binv);
    t.u[1] = pk2(a0[2] * inv + bA[2] * binv, a0[3] * inv + bA[3] * binv);
    t.u[2] = pk2(a1[0] * inv + bB[0] * binv, a1[1] * inv + bB[1] * binv);
    t.u[3] = pk2(a1[2] * inv + bB[2] * binv, a1[3] * inv + bB[3] * binv);
    ef[k2] = t.v;
  }
#pragma unroll
  for (int i = 0; i < 32; i++) wA[i] = ldfrag(pk + 176 * 512, i, l);  // w3b pi
#pragma unroll
  for (int kt = 0; kt < 4; kt++)
#pragma unroll
    for (int ft = 0; ft < 8; ft++)
      acc[ft] = mf(wB[kt * 8 + ft], ef[kt], kt == 0 ? Z : acc[ft]);
#pragma unroll
  for (int k2 = 0; k2 < 4; k2++) {  // +b3a relu
    f32x4 bA = *(const f32x4*)(b3a + (2 * k2) * 16 + h * 4);
    f32x4 bB = *(const f32x4*)(b3a + (2 * k2 + 1) * 16 + h * 4);
    f32x4 a0 = acc[2 * k2], a1 = acc[2 * k2 + 1];
    union { unsigned u[4]; bf16x8 v; } t;
    t.u[0] = pk2(fmaxf(a0[0] + bA[0], 0.f), fmaxf(a0[1] + bA[1], 0.f));
    t.u[1] = pk2(fmaxf(a0[2] + bA[2], 0.f), fmaxf(a0[3] + bA[3], 0.f));
    t.u[2] = pk2(fmaxf(a1[0] + bB[0], 0.f), fmaxf(a1[1] + bB[1], 0.f));
    t.u[3] = pk2(fmaxf(a1[2] + bB[2], 0.f), fmaxf(a1[3] + bB[3], 0.f));
    ef[k2] = t.v;
  }
#pragma unroll
  for (int i = 0; i < 32; i++) wB[i] = ldfrag(pk + 208 * 512, i, l);  // w4a_s pi
#pragma unroll
  for (int kt = 0; kt < 4; kt++)
#pragma unroll
    for (int ft = 0; ft < 8; ft++)
      acc[ft] = mf(wA[kt * 8 + ft], ef[kt], kt == 0 ? Z : acc[ft]);
#pragma unroll
  for (int k2 = 0; k2 < 4; k2++) {  // +b3b -> efn (= n)
    f32x4 bA = *(const f32x4*)(b3b + (2 * k2) * 16 + h * 4);
    f32x4 bB = *(const f32x4*)(b3b + (2 * k2 + 1) * 16 + h * 4);
    f32x4 a0 = acc[2 * k2], a1 = acc[2 * k2 + 1];
    union { unsigned u[4]; bf16x8 v; } t;
    t.u[0] = pk2(a0[0] + bA[0], a0[1] + bA[1]);
    t.u[1] = pk2(a0[2] + bA[2], a0[3] + bA[3]);
    t.u[2] = pk2(a1[0] + bB[0], a1[1] + bB[1]);
    t.u[3] = pk2(a1[2] + bB[2], a1[3] + bB[3]);
    efn[k2] = t.v;
  }
#pragma unroll
  for (int i = 0; i < 32; i++) wA[i] = ldfrag(pk + 240 * 512, i, l);  // w4a_r pi
#pragma unroll
  for (int kt = 0; kt < 4; kt++)  // s4 = n@w4a_s + c2   (c2 = b2b@w4a_e fold)
#pragma unroll
    for (int ft = 0; ft < 8; ft++)
      acc[ft] = mf(wB[kt * 8 + ft], efn[kt], kt == 0 ? Z : acc[ft]);
  float* s4o = s4 + (b * NN + j) * H;
#pragma unroll
  for (int ft = 0; ft < 8; ft++) {
    f32x4 cc = *(const f32x4*)(c2 + ft * 16 + h * 4);
    f32x4 o = acc[ft];
    o[0] += cc[0]; o[1] += cc[1]; o[2] += cc[2]; o[3] += cc[3];
    *reinterpret_cast<f32x4*>(s4o + ft * 16 + h * 4) = o;
  }
#pragma unroll
  for (int kt = 0; kt < 4; kt++)  // r4 = n@w4a_r + b4a
#pragma unroll
    for (int ft = 0; ft < 8; ft++)
      acc[ft] = mf(wA[kt * 8 + ft], efn[kt], kt == 0 ? Z : acc[ft]);
  float* r4o = r4 + (b * NN + j) * H;
#pragma unroll
  for (int ft = 0; ft < 8; ft++) {
    f32x4 bb = *(const f32x4*)(b4a + ft * 16 + h * 4);
    f32x4 o = acc[ft];
    o[0] += bb[0]; o[1] += bb[1]; o[2] += bb[2]; o[3] += bb[3];
    *reinterpret_cast<f32x4*>(r4o + ft * 16 + h * 4) = o;
  }
}

// ---- edge kernel: 1 wave/block, (b, sender-quarter p, edge-quarter q),
// 16 tiles, weights for all 4 stages register-resident; pi-chained; no LDS.
__global__ __launch_bounds__(64, 1) void edge_kernel(
    const float* __restrict__ sproj, const float* __restrict__ rproj,
    const float* __restrict__ s4, const float* __restrict__ r4,
    const u16* __restrict__ pk, const float* __restrict__ c4,
    float* __restrict__ out) {
  int blk = blockIdx.x, b = blk >> 4, p = (blk >> 2) & 3, q = blk & 3;
  int l = threadIdx.x, m = l & 15, h = l >> 4;
  bf16x8 w2[32], wA[32], wB[32], wo[4];
#pragma unroll
  for (int i2 = 0; i2 < 32; i2++) w2[i2] = ldfrag(pk + 112 * 512, i2, l);  // w2b nat
#pragma unroll
  for (int i2 = 0; i2 < 32; i2++) wA[i2] = ldfrag(pk + 272 * 512, i2, l);  // w4a_e pi
#pragma unroll
  for (int i2 = 0; i2 < 32; i2++) wB[i2] = ldfrag(pk + 304 * 512, i2, l);  // w4b pi
#pragma unroll
  for (int i2 = 0; i2 < 4; i2++) wo[i2] = ldfrag(pk + 336 * 512, i2, l);   // wout pi
  f32x4 c4v = *(const f32x4*)(c4 + h * 4);
  const f32x4 Z = {0.f, 0.f, 0.f, 0.f};
  int jj = q * 16 + m;
  const float* spb = sproj + b * NN * H;
  const float* rpb = rproj + b * NN * H;
  const float* s4b = s4 + b * NN * H;
  const float* r4b = r4 + b * NN * H;
  for (int t = 0; t < 16; t++) {
    int i = p * 16 + t;
    int jn = jj + (jj >= i ? 1 : 0); jn = jn > 63 ? 63 : jn;
    const float* rp = rpb + jn * H;
    const float* sp = spb + i * H;
    f32x4 acc[8]; bf16x8 ef[4];
    // stage 1: t = relu(sp+rp) built in regs -> e_hat = t @ w2b
#pragma unroll
    for (int kt = 0; kt < 4; kt++) {
      f32x4 r0 = *(const f32x4*)(rp + kt * 32 + h * 8);
      f32x4 r1 = *(const f32x4*)(rp + kt * 32 + h * 8 + 4);
      f32x4 s0 = *(const f32x4*)(sp + kt * 32 + h * 8);
      f32x4 s1 = *(const f32x4*)(sp + kt * 32 + h * 8 + 4);
      union { unsigned u[4]; bf16x8 v; } tbv;
      tbv.u[0] = pk2(fmaxf(r0[0] + s0[0], 0.f), fmaxf(r0[1] + s0[1], 0.f));
      tbv.u[1] = pk2(fmaxf(r0[2] + s0[2], 0.f), fmaxf(r0[3] + s0[3], 0.f));
      tbv.u[2] = pk2(fmaxf(r1[0] + s1[0], 0.f), fmaxf(r1[1] + s1[1], 0.f));
      tbv.u[3] = pk2(fmaxf(r1[2] + s1[2], 0.f), fmaxf(r1[3] + s1[3], 0.f));
#pragma unroll
      for (int ft = 0; ft < 8; ft++)
        acc[ft] = mf(w2[kt * 8 + ft], tbv.v, kt == 0 ? Z : acc[ft]);
    }
#pragma unroll
    for (int k2 = 0; k2 < 4; k2++) {  // pack (b2b folded upstream into s4')
      f32x4 a0 = acc[2 * k2], a1 = acc[2 * k2 + 1];
      union { unsigned u[4]; bf16x8 v; } t2;
      t2.u[0] = pk2(a0[0], a0[1]); t2.u[1] = pk2(a0[2], a0[3]);
      t2.u[2] = pk2(a1[0], a1[1]); t2.u[3] = pk2(a1[2], a1[3]);
      ef[k2] = t2.v;
    }
    // stage 2: u = relu(e@w4a_e + s4'[i] + r4[jn])
#pragma unroll
    for (int kt = 0; kt < 4; kt++)
#pragma unroll
      for (int ft = 0; ft < 8; ft++)
        acc[ft] = mf(wA[kt * 8 + ft], ef[kt], kt == 0 ? Z : acc[ft]);
    {
      const float* s4p = s4b + i * H;
      const float* r4p = r4b + jn * H;
#pragma unroll
      for (int k2 = 0; k2 < 4; k2++) {
        f32x4 sA = *(const f32x4*)(s4p + (2 * k2) * 16 + h * 4);
        f32x4 sB = *(const f32x4*)(s4p + (2 * k2 + 1) * 16 + h * 4);
        f32x4 rA = *(const f32x4*)(r4p + (2 * k2) * 16 + h * 4);
        f32x4 rB = *(const f32x4*)(r4p + (2 * k2 + 1) * 16 + h * 4);
        f32x4 a0 = acc[2 * k2], a1 = acc[2 * k2 + 1];
        union { unsigned u[4]; bf16x8 v; } t2;
        t2.u[0] = pk2(fmaxf(a0[0] + sA[0] + rA[0], 0.f), fmaxf(a0[1] + sA[1] + rA[1], 0.f));
        t2.u[1] = pk2(fmaxf(a0[2] + sA[2] + rA[2], 0.f), fmaxf(a0[3] + sA[3] + rA[3], 0.f));
        t2.u[2] = pk2(fmaxf(a1[0] + sB[0] + rB[0], 0.f), fmaxf(a1[1] + sB[1] + rB[1], 0.f));
        t2.u[3] = pk2(fmaxf(a1[2] + sB[2] + rB[2], 0.f), fmaxf(a1[3] + sB[3] + rB[3], 0.f));
        ef[k2] = t2.v;
      }
    }
    // stage 3: e2_hat = u @ w4b   (b4b folded into c4)
#pragma unroll
    for (int kt = 0; kt < 4; kt++)
#pragma unroll
      for (int ft = 0; ft < 8; ft++)
        acc[ft] = mf(wB[kt * 8 + ft], ef[kt], kt == 0 ? Z : acc[ft]);
#pragma unroll
    for (int k2 = 0; k2 < 4; k2++) {
      f32x4 a0 = acc[2 * k2], a1 = acc[2 * k2 + 1];
      union { unsigned u[4]; bf16x8 v; } t2;
      t2.u[0] = pk2(a0[0], a0[1]); t2.u[1] = pk2(a0[2], a0[3]);
      t2.u[2] = pk2(a1[0], a1[1]); t2.u[3] = pk2(a1[2], a1[3]);
      ef[k2] = t2.v;
    }
    // stage 4: out = e2@wout + c4
    f32x4 a4 = Z;
#pragma unroll
    for (int kt = 0; kt < 4; kt++) a4 = mf(wo[kt], ef[kt], a4);
    if (jj < 63) {
      f32x4 o;
      o[0] = a4[0] + c4v[0]; o[1] = a4[1] + c4v[1];
      o[2] = a4[2] + c4v[2]; o[3] = a4[3] + c4v[3];
      *reinterpret_cast<f32x4*>(out + (b * NE + i * 63 + jj) * 16 + h * 4) = o;
    }
  }
}

extern "C" void kernel_launch(void* const* d_in, const int* in_sizes, int n_in,
                              void* d_out, int out_size, void* d_ws, size_t ws_size,
                              hipStream_t stream) {
  const float* x    = (const float*)d_in[0];
  // d_in[1]=rel_rec, d_in[2]=rel_send: one-hot fully-connected, hardcoded.
  const float* w1a  = (const float*)d_in[3];
  const float* b1a  = (const float*)d_in[4];
  const float* w1b  = (const float*)d_in[5];
  const float* b1b  = (const float*)d_in[6];
  const float* w2a  = (const float*)d_in[7];
  const float* b2a  = (const float*)d_in[8];
  const float* w2b  = (const float*)d_in[9];
  const float* b2b  = (const float*)d_in[10];
  const float* w3a  = (const float*)d_in[11];
  const float* b3a  = (const float*)d_in[12];
  const float* w3b  = (const float*)d_in[13];
  const float* b3b  = (const float*)d_in[14];
  const float* w4a  = (const float*)d_in[15];
  const float* b4a  = (const float*)d_in[16];
  const float* w4b  = (const float*)d_in[17];
  const float* b4b  = (const float*)d_in[18];
  const float* wout = (const float*)d_in[19];
  const float* bout = (const float*)d_in[20];
  float* out = (float*)d_out;

  float* sproj = (float*)d_ws;
  float* rproj = sproj + 524288;
  float* s4    = rproj + 524288;
  float* r4    = s4 + 524288;
  u16* pkw     = (u16*)(r4 + 524288);   // 340 frags * 512 u16
  float* c2    = (float*)(pkw + 174080);
  float* c4    = c2 + 128;

  prepack_kernel<<<dim3(32, 13), 64, 0, stream>>>(
      w1a, w1b, w2a, w2b, w3a, w3b, w4a, w4b, wout, b2b, b4b, bout, pkw, c2, c4);
  node_kernel<<<256, 64, 0, stream>>>(x, pkw, b1a, b1b, b2a, sproj, rproj);
  agg_kernel<<<256, 256, 0, stream>>>(sproj, rproj, pkw, b2b, b3a, b3b, b4a, c2, s4, r4);
  edge_kernel<<<1024, 64, 0, stream>>>(sproj, rproj, s4, r4, pkw, c4, out);
}

// Round 5
// 122.141 us; speedup vs baseline: 1.1255x; 1.1255x over previous
//
#include <hip/hip_runtime.h>
#include <hip/hip_bf16.h>

// NRI Encoder, MI355X. Fully factorized + pi-permuted-weight register chain.
// R5: pin weight fragments in registers with an asm memory fence so the
// allocator cannot rematerialize the global loads inside the tile loop
// (R4 diagnosis: VGPR_Count=248 << 400 needed => per-tile L2 re-streaming).

#define DI __device__ __forceinline__

typedef short bf16x8 __attribute__((ext_vector_type(8)));
typedef float f32x4 __attribute__((ext_vector_type(4)));
typedef unsigned short u16;

static constexpr int NN = 64, NE = 4032, H = 128;

DI u16 f2bf(float f) {
  union { float f; unsigned u; } v; v.f = f;
  unsigned u = v.u;
  return (u16)((u + 0x7fffu + ((u >> 16) & 1u)) >> 16);
}
DI unsigned pk2(float a, float b) {
  union { __hip_bfloat162 h; unsigned u; } c;
  c.h = __float22bfloat162_rn(float2{a, b});
  return c.u;
}
DI f32x4 mf(bf16x8 a, bf16x8 b, f32x4 c) {
  return __builtin_amdgcn_mfma_f32_16x16x32_bf16(a, b, c, 0, 0, 0);
}
DI bf16x8 ldfrag(const u16* __restrict__ p, int idx, int l) {
  return *reinterpret_cast<const bf16x8*>(p + (idx * 64 + l) * 8);
}
#define PIN_REGS() asm volatile("" ::: "memory")

// ---- prepack: all weights -> MFMA A-frag-of-W^T order; pi row-permutation
// for chained stages; also computes folded bias vectors c2, c4.
// frag layout: dst[(frag*64+lane)*8+jj] = W[roff + row(kt,h,jj)][ct*16+(lane&15)]
//   natural: row = kt*32 + h*8 + jj         (stage inputs built from scratch)
//   pi:      row = kt*32 + (jj>>2)*16 + h*4 + (jj&3)   (chained stages)
__global__ __launch_bounds__(64) void prepack_kernel(
    const float* __restrict__ w1a, const float* __restrict__ w1b,
    const float* __restrict__ w2a, const float* __restrict__ w2b,
    const float* __restrict__ w3a, const float* __restrict__ w3b,
    const float* __restrict__ w4a, const float* __restrict__ w4b,
    const float* __restrict__ wout,
    const float* __restrict__ b2b, const float* __restrict__ b4b,
    const float* __restrict__ bout,
    u16* __restrict__ pk, float* __restrict__ c2, float* __restrict__ c4) {
  int seg = blockIdx.y, f = blockIdx.x, l = threadIdx.x;
  if (seg == 12) {  // folded biases
    if (f < 2) {
      int o = f * 64 + l;
      float s = 0.f;
      for (int k = 0; k < 128; k++) s += b2b[k] * w4a[(256 + k) * 128 + o];
      c2[o] = s;
    } else if (f == 2 && l < 16) {
      float s = bout[l];
      for (int k = 0; k < 128; k++) s += b4b[k] * wout[k * 16 + l];
      c4[l] = s;
    }
    return;
  }
  const float* src; int foff, nfrag, nct, roff, ld, pi;
  switch (seg) {
    case 0:  src = w1a;  foff = 0;   nfrag = 16; nct = 8; roff = 0;   ld = 128; pi = 0; break;
    case 1:  src = w1b;  foff = 16;  nfrag = 32; nct = 8; roff = 0;   ld = 128; pi = 1; break;
    case 2:  src = w2a;  foff = 48;  nfrag = 32; nct = 8; roff = 0;   ld = 128; pi = 1; break;
    case 3:  src = w2a;  foff = 80;  nfrag = 32; nct = 8; roff = 128; ld = 128; pi = 1; break;
    case 4:  src = w2b;  foff = 112; nfrag = 32; nct = 8; roff = 0;   ld = 128; pi = 0; break;
    case 5:  src = w3a;  foff = 144; nfrag = 32; nct = 8; roff = 0;   ld = 128; pi = 1; break;
    case 6:  src = w3b;  foff = 176; nfrag = 32; nct = 8; roff = 0;   ld = 128; pi = 1; break;
    case 7:  src = w4a;  foff = 208; nfrag = 32; nct = 8; roff = 0;   ld = 128; pi = 1; break;
    case 8:  src = w4a;  foff = 240; nfrag = 32; nct = 8; roff = 128; ld = 128; pi = 1; break;
    case 9:  src = w4a;  foff = 272; nfrag = 32; nct = 8; roff = 256; ld = 128; pi = 1; break;
    case 10: src = w4b;  foff = 304; nfrag = 32; nct = 8; roff = 0;   ld = 128; pi = 1; break;
    default: src = wout; foff = 336; nfrag = 4;  nct = 1; roff = 0;   ld = 16;  pi = 1; break;
  }
  if (f >= nfrag) return;
  int kt = f / nct, ct = f % nct, h = l >> 4, mm = l & 15;
  union { u16 u[8]; uint4 q; } o;
#pragma unroll
  for (int jj = 0; jj < 8; jj++) {
    int row = pi ? (kt * 32 + (jj >> 2) * 16 + h * 4 + (jj & 3))
                 : (kt * 32 + h * 8 + jj);
    o.u[jj] = f2bf(src[(roff + row) * ld + ct * 16 + mm]);
  }
  *reinterpret_cast<uint4*>(pk + ((foff + f) * 64 + l) * 8) = o.q;
}

// ---- node kernel: x -> h1 -> h -> sproj, rproj. 256 blocks x 1 wave,
// per-stage weight reload into double-buffered register sets (pinned).
__global__ __launch_bounds__(64, 1) void node_kernel(
    const float* __restrict__ x, const u16* __restrict__ pk,
    const float* __restrict__ b1a, const float* __restrict__ b1b,
    const float* __restrict__ b2a,
    float* __restrict__ sproj, float* __restrict__ rproj) {
  int blk = blockIdx.x, b = blk >> 2, nq = blk & 3;
  int l = threadIdx.x, m = l & 15, h = l >> 4;
  int node = nq * 16 + m;
  const f32x4 Z = {0.f, 0.f, 0.f, 0.f};
  bf16x8 wA[32], wB[32];
#pragma unroll
  for (int i = 0; i < 16; i++) wA[i] = ldfrag(pk, i, l);          // w1a
#pragma unroll
  for (int i = 0; i < 32; i++) wB[i] = ldfrag(pk + 16 * 512, i, l);  // w1b (pi)
  PIN_REGS();
  f32x4 acc[8]; bf16x8 ef[4];
  const float* xb = x + (b * NN + node) * 64;
#pragma unroll
  for (int kt = 0; kt < 2; kt++) {  // stage 1, K=64
    f32x4 a0 = *(const f32x4*)(xb + kt * 32 + h * 8);
    f32x4 a1 = *(const f32x4*)(xb + kt * 32 + h * 8 + 4);
    union { unsigned u[4]; bf16x8 v; } t;
    t.u[0] = pk2(a0[0], a0[1]); t.u[1] = pk2(a0[2], a0[3]);
    t.u[2] = pk2(a1[0], a1[1]); t.u[3] = pk2(a1[2], a1[3]);
#pragma unroll
    for (int ft = 0; ft < 8; ft++)
      acc[ft] = mf(wA[kt * 8 + ft], t.v, kt == 0 ? Z : acc[ft]);
  }
#pragma unroll
  for (int k2 = 0; k2 < 4; k2++) {  // +b1a, relu -> ef
    f32x4 bA = *(const f32x4*)(b1a + (2 * k2) * 16 + h * 4);
    f32x4 bB = *(const f32x4*)(b1a + (2 * k2 + 1) * 16 + h * 4);
    f32x4 a0 = acc[2 * k2], a1 = acc[2 * k2 + 1];
    union { unsigned u[4]; bf16x8 v; } t;
    t.u[0] = pk2(fmaxf(a0[0] + bA[0], 0.f), fmaxf(a0[1] + bA[1], 0.f));
    t.u[1] = pk2(fmaxf(a0[2] + bA[2], 0.f), fmaxf(a0[3] + bA[3], 0.f));
    t.u[2] = pk2(fmaxf(a1[0] + bB[0], 0.f), fmaxf(a1[1] + bB[1], 0.f));
    t.u[3] = pk2(fmaxf(a1[2] + bB[2], 0.f), fmaxf(a1[3] + bB[3], 0.f));
    ef[k2] = t.v;
  }
#pragma unroll
  for (int i = 0; i < 32; i++) wA[i] = ldfrag(pk + 48 * 512, i, l);  // w2a_s (pi)
  PIN_REGS();
#pragma unroll
  for (int kt = 0; kt < 4; kt++)  // stage 2 (wB = w1b)
#pragma unroll
    for (int ft = 0; ft < 8; ft++)
      acc[ft] = mf(wB[kt * 8 + ft], ef[kt], kt == 0 ? Z : acc[ft]);
  bf16x8 efh[4];
#pragma unroll
  for (int k2 = 0; k2 < 4; k2++) {  // +b1b -> efh
    f32x4 bA = *(const f32x4*)(b1b + (2 * k2) * 16 + h * 4);
    f32x4 bB = *(const f32x4*)(b1b + (2 * k2 + 1) * 16 + h * 4);
    f32x4 a0 = acc[2 * k2], a1 = acc[2 * k2 + 1];
    union { unsigned u[4]; bf16x8 v; } t;
    t.u[0] = pk2(a0[0] + bA[0], a0[1] + bA[1]);
    t.u[1] = pk2(a0[2] + bA[2], a0[3] + bA[3]);
    t.u[2] = pk2(a1[0] + bB[0], a1[1] + bB[1]);
    t.u[3] = pk2(a1[2] + bB[2], a1[3] + bB[3]);
    efh[k2] = t.v;
  }
#pragma unroll
  for (int i = 0; i < 32; i++) wB[i] = ldfrag(pk + 80 * 512, i, l);  // w2a_r (pi)
  PIN_REGS();
#pragma unroll
  for (int kt = 0; kt < 4; kt++)  // stage 3: sproj (wA)
#pragma unroll
    for (int ft = 0; ft < 8; ft++)
      acc[ft] = mf(wA[kt * 8 + ft], efh[kt], kt == 0 ? Z : acc[ft]);
  float* spo = sproj + (b * NN + node) * H;
#pragma unroll
  for (int ft = 0; ft < 8; ft++)
    *reinterpret_cast<f32x4*>(spo + ft * 16 + h * 4) = acc[ft];
#pragma unroll
  for (int kt = 0; kt < 4; kt++)  // stage 4: rproj (wB)
#pragma unroll
    for (int ft = 0; ft < 8; ft++)
      acc[ft] = mf(wB[kt * 8 + ft], efh[kt], kt == 0 ? Z : acc[ft]);
  float* rpo = rproj + (b * NN + node) * H;
#pragma unroll
  for (int ft = 0; ft < 8; ft++) {
    f32x4 bb = *(const f32x4*)(b2a + ft * 16 + h * 4);
    f32x4 o = acc[ft];
    o[0] += bb[0]; o[1] += bb[1]; o[2] += bb[2]; o[3] += bb[3];
    *reinterpret_cast<f32x4*>(rpo + ft * 16 + h * 4) = o;
  }
}

// ---- agg kernel: relu-sum over senders (4 waves) + chain to s4, r4 (wave 0)
__global__ __launch_bounds__(256, 1) void agg_kernel(
    const float* __restrict__ sproj, const float* __restrict__ rproj,
    const u16* __restrict__ pk,
    const float* __restrict__ b2b, const float* __restrict__ b3a,
    const float* __restrict__ b3b, const float* __restrict__ b4a,
    const float* __restrict__ c2,
    float* __restrict__ s4, float* __restrict__ r4) {
  __shared__ float lred[3][32][65];
  int blk = blockIdx.x, b = blk >> 2, jq = blk & 3;
  int tid = threadIdx.x, l = tid & 63, w = tid >> 6, m = l & 15, h = l >> 4;
  int j = jq * 16 + m;
  const float* rpb = rproj + (b * NN + j) * H;
  f32x4 rpv[8], accS[8];
#pragma unroll
  for (int k = 0; k < 8; k++) {
    rpv[k] = *(const f32x4*)(rpb + (k >> 1) * 32 + h * 8 + (k & 1) * 4);
    accS[k] = f32x4{0.f, 0.f, 0.f, 0.f};
  }
  const float* spb = sproj + b * NN * H;
  for (int i = w * 16; i < w * 16 + 16; i++) {
    const float* sp = spb + i * H;
#pragma unroll
    for (int k = 0; k < 8; k++) {
      f32x4 s = *(const f32x4*)(sp + (k >> 1) * 32 + h * 8 + (k & 1) * 4);
      f32x4 t = s + rpv[k];
      t[0] = fmaxf(t[0], 0.f); t[1] = fmaxf(t[1], 0.f);
      t[2] = fmaxf(t[2], 0.f); t[3] = fmaxf(t[3], 0.f);
      accS[k] += t;
    }
  }
  if (w == jq) {  // subtract self-loop i==j
    const float* sp = spb + j * H;
#pragma unroll
    for (int k = 0; k < 8; k++) {
      f32x4 s = *(const f32x4*)(sp + (k >> 1) * 32 + h * 8 + (k & 1) * 4);
      f32x4 t = s + rpv[k];
      accS[k][0] -= fmaxf(t[0], 0.f); accS[k][1] -= fmaxf(t[1], 0.f);
      accS[k][2] -= fmaxf(t[2], 0.f); accS[k][3] -= fmaxf(t[3], 0.f);
    }
  }
  if (w > 0) {
#pragma unroll
    for (int k = 0; k < 8; k++)
#pragma unroll
      for (int qq = 0; qq < 4; qq++) lred[w - 1][k * 4 + qq][l] = accS[k][qq];
  }
  __syncthreads();
  if (w != 0) return;
#pragma unroll
  for (int ww = 0; ww < 3; ww++)
#pragma unroll
    for (int k = 0; k < 8; k++)
#pragma unroll
      for (int qq = 0; qq < 4; qq++) accS[k][qq] += lred[ww][k * 4 + qq][l];

  const f32x4 Z = {0.f, 0.f, 0.f, 0.f};
  bf16x8 tb[4];
#pragma unroll
  for (int k2 = 0; k2 < 4; k2++) {
    f32x4 a0 = accS[2 * k2], a1 = accS[2 * k2 + 1];
    union { unsigned u[4]; bf16x8 v; } t;
    t.u[0] = pk2(a0[0], a0[1]); t.u[1] = pk2(a0[2], a0[3]);
    t.u[2] = pk2(a1[0], a1[1]); t.u[3] = pk2(a1[2], a1[3]);
    tb[k2] = t.v;
  }
  bf16x8 wA[32], wB[32]; f32x4 acc[8]; bf16x8 ef[4], efn[4];
#pragma unroll
  for (int i = 0; i < 32; i++) wA[i] = ldfrag(pk + 112 * 512, i, l);  // w2b nat
#pragma unroll
  for (int i = 0; i < 32; i++) wB[i] = ldfrag(pk + 144 * 512, i, l);  // w3a pi
  PIN_REGS();
#pragma unroll
  for (int kt = 0; kt < 4; kt++)
#pragma unroll
    for (int ft = 0; ft < 8; ft++)
      acc[ft] = mf(wA[kt * 8 + ft], tb[kt], kt == 0 ? Z : acc[ft]);
  const float inv = 1.0f / (63.0f + 1e-6f);
  const float binv = 63.0f * inv;
#pragma unroll
  for (int k2 = 0; k2 < 4; k2++) {  // agg = (sum@w2b + 63 b2b)/63.000001
    f32x4 bA = *(const f32x4*)(b2b + (2 * k2) * 16 + h * 4);
    f32x4 bB = *(const f32x4*)(b2b + (2 * k2 + 1) * 16 + h * 4);
    f32x4 a0 = acc[2 * k2], a1 = acc[2 * k2 + 1];
    union { unsigned u[4]; bf16x8 v; } t;
    t.u[0] = pk2(a0[0] * inv + bA[0] * binv, a0[1] * inv + bA[1] * binv);
    t.u[1] = pk2(a0[2] * inv + bA[2] * binv, a0[3] * inv + bA[3] * binv);
    t.u[2] = pk2(a1[0] * inv + bB[0] * binv, a1[1] * inv + bB[1] * binv);
    t.u[3] = pk2(a1[2] * inv + bB[2] * binv, a1[3] * inv + bB[3] * binv);
    ef[k2] = t.v;
  }
#pragma unroll
  for (int i = 0; i < 32; i++) wA[i] = ldfrag(pk + 176 * 512, i, l);  // w3b pi
  PIN_REGS();
#pragma unroll
  for (int kt = 0; kt < 4; kt++)
#pragma unroll
    for (int ft = 0; ft < 8; ft++)
      acc[ft] = mf(wB[kt * 8 + ft], ef[kt], kt == 0 ? Z : acc[ft]);
#pragma unroll
  for (int k2 = 0; k2 < 4; k2++) {  // +b3a relu
    f32x4 bA = *(const f32x4*)(b3a + (2 * k2) * 16 + h * 4);
    f32x4 bB = *(const f32x4*)(b3a + (2 * k2 + 1) * 16 + h * 4);
    f32x4 a0 = acc[2 * k2], a1 = acc[2 * k2 + 1];
    union { unsigned u[4]; bf16x8 v; } t;
    t.u[0] = pk2(fmaxf(a0[0] + bA[0], 0.f), fmaxf(a0[1] + bA[1], 0.f));
    t.u[1] = pk2(fmaxf(a0[2] + bA[2], 0.f), fmaxf(a0[3] + bA[3], 0.f));
    t.u[2] = pk2(fmaxf(a1[0] + bB[0], 0.f), fmaxf(a1[1] + bB[1], 0.f));
    t.u[3] = pk2(fmaxf(a1[2] + bB[2], 0.f), fmaxf(a1[3] + bB[3], 0.f));
    ef[k2] = t.v;
  }
#pragma unroll
  for (int i = 0; i < 32; i++) wB[i] = ldfrag(pk + 208 * 512, i, l);  // w4a_s pi
  PIN_REGS();
#pragma unroll
  for (int kt = 0; kt < 4; kt++)
#pragma unroll
    for (int ft = 0; ft < 8; ft++)
      acc[ft] = mf(wA[kt * 8 + ft], ef[kt], kt == 0 ? Z : acc[ft]);
#pragma unroll
  for (int k2 = 0; k2 < 4; k2++) {  // +b3b -> efn (= n)
    f32x4 bA = *(const f32x4*)(b3b + (2 * k2) * 16 + h * 4);
    f32x4 bB = *(const f32x4*)(b3b + (2 * k2 + 1) * 16 + h * 4);
    f32x4 a0 = acc[2 * k2], a1 = acc[2 * k2 + 1];
    union { unsigned u[4]; bf16x8 v; } t;
    t.u[0] = pk2(a0[0] + bA[0], a0[1] + bA[1]);
    t.u[1] = pk2(a0[2] + bA[2], a0[3] + bA[3]);
    t.u[2] = pk2(a1[0] + bB[0], a1[1] + bB[1]);
    t.u[3] = pk2(a1[2] + bB[2], a1[3] + bB[3]);
    efn[k2] = t.v;
  }
#pragma unroll
  for (int i = 0; i < 32; i++) wA[i] = ldfrag(pk + 240 * 512, i, l);  // w4a_r pi
  PIN_REGS();
#pragma unroll
  for (int kt = 0; kt < 4; kt++)  // s4 = n@w4a_s + c2   (c2 = b2b@w4a_e fold)
#pragma unroll
    for (int ft = 0; ft < 8; ft++)
      acc[ft] = mf(wB[kt * 8 + ft], efn[kt], kt == 0 ? Z : acc[ft]);
  float* s4o = s4 + (b * NN + j) * H;
#pragma unroll
  for (int ft = 0; ft < 8; ft++) {
    f32x4 cc = *(const f32x4*)(c2 + ft * 16 + h * 4);
    f32x4 o = acc[ft];
    o[0] += cc[0]; o[1] += cc[1]; o[2] += cc[2]; o[3] += cc[3];
    *reinterpret_cast<f32x4*>(s4o + ft * 16 + h * 4) = o;
  }
#pragma unroll
  for (int kt = 0; kt < 4; kt++)  // r4 = n@w4a_r + b4a
#pragma unroll
    for (int ft = 0; ft < 8; ft++)
      acc[ft] = mf(wA[kt * 8 + ft], efn[kt], kt == 0 ? Z : acc[ft]);
  float* r4o = r4 + (b * NN + j) * H;
#pragma unroll
  for (int ft = 0; ft < 8; ft++) {
    f32x4 bb = *(const f32x4*)(b4a + ft * 16 + h * 4);
    f32x4 o = acc[ft];
    o[0] += bb[0]; o[1] += bb[1]; o[2] += bb[2]; o[3] += bb[3];
    *reinterpret_cast<f32x4*>(r4o + ft * 16 + h * 4) = o;
  }
}

// ---- edge kernel: 1 wave/block, (b, sender-quarter p, edge-quarter q),
// 16 tiles, weights for stages 1-3 register-PINNED (384 VGPR); pi-chained;
// no LDS, no barriers. wout/c4 reloaded per tile (L1-hot, unpinned).
__global__ __launch_bounds__(64, 1) void edge_kernel(
    const float* __restrict__ sproj, const float* __restrict__ rproj,
    const float* __restrict__ s4, const float* __restrict__ r4,
    const u16* __restrict__ pk, const float* __restrict__ c4,
    float* __restrict__ out) {
  int blk = blockIdx.x, b = blk >> 4, p = (blk >> 2) & 3, q = blk & 3;
  int l = threadIdx.x, m = l & 15, h = l >> 4;
  bf16x8 w2[32], wA[32], wB[32];
#pragma unroll
  for (int i2 = 0; i2 < 32; i2++) w2[i2] = ldfrag(pk + 112 * 512, i2, l);  // w2b nat
#pragma unroll
  for (int i2 = 0; i2 < 32; i2++) wA[i2] = ldfrag(pk + 272 * 512, i2, l);  // w4a_e pi
#pragma unroll
  for (int i2 = 0; i2 < 32; i2++) wB[i2] = ldfrag(pk + 304 * 512, i2, l);  // w4b pi
  PIN_REGS();  // forbid rematerializing the 96 fragments inside the loop
  const f32x4 Z = {0.f, 0.f, 0.f, 0.f};
  int jj = q * 16 + m;
  const float* spb = sproj + b * NN * H;
  const float* rpb = rproj + b * NN * H;
  const float* s4b = s4 + b * NN * H;
  const float* r4b = r4 + b * NN * H;
  for (int t = 0; t < 16; t++) {
    int i = p * 16 + t;
    int jn = jj + (jj >= i ? 1 : 0); jn = jn > 63 ? 63 : jn;
    const float* rp = rpb + jn * H;
    const float* sp = spb + i * H;
    f32x4 acc[8]; bf16x8 ef[4];
    // stage 1: t = relu(sp+rp) built in regs -> e_hat = t @ w2b
#pragma unroll
    for (int kt = 0; kt < 4; kt++) {
      f32x4 r0 = *(const f32x4*)(rp + kt * 32 + h * 8);
      f32x4 r1 = *(const f32x4*)(rp + kt * 32 + h * 8 + 4);
      f32x4 s0 = *(const f32x4*)(sp + kt * 32 + h * 8);
      f32x4 s1 = *(const f32x4*)(sp + kt * 32 + h * 8 + 4);
      union { unsigned u[4]; bf16x8 v; } tbv;
      tbv.u[0] = pk2(fmaxf(r0[0] + s0[0], 0.f), fmaxf(r0[1] + s0[1], 0.f));
      tbv.u[1] = pk2(fmaxf(r0[2] + s0[2], 0.f), fmaxf(r0[3] + s0[3], 0.f));
      tbv.u[2] = pk2(fmaxf(r1[0] + s1[0], 0.f), fmaxf(r1[1] + s1[1], 0.f));
      tbv.u[3] = pk2(fmaxf(r1[2] + s1[2], 0.f), fmaxf(r1[3] + s1[3], 0.f));
#pragma unroll
      for (int ft = 0; ft < 8; ft++)
        acc[ft] = mf(w2[kt * 8 + ft], tbv.v, kt == 0 ? Z : acc[ft]);
    }
#pragma unroll
    for (int k2 = 0; k2 < 4; k2++) {  // pack (b2b folded upstream into s4')
      f32x4 a0 = acc[2 * k2], a1 = acc[2 * k2 + 1];
      union { unsigned u[4]; bf16x8 v; } t2;
      t2.u[0] = pk2(a0[0], a0[1]); t2.u[1] = pk2(a0[2], a0[3]);
      t2.u[2] = pk2(a1[0], a1[1]); t2.u[3] = pk2(a1[2], a1[3]);
      ef[k2] = t2.v;
    }
    // stage 2: u = relu(e@w4a_e + s4'[i] + r4[jn])
#pragma unroll
    for (int kt = 0; kt < 4; kt++)
#pragma unroll
      for (int ft = 0; ft < 8; ft++)
        acc[ft] = mf(wA[kt * 8 + ft], ef[kt], kt == 0 ? Z : acc[ft]);
    {
      const float* s4p = s4b + i * H;
      const float* r4p = r4b + jn * H;
#pragma unroll
      for (int k2 = 0; k2 < 4; k2++) {
        f32x4 sA = *(const f32x4*)(s4p + (2 * k2) * 16 + h * 4);
        f32x4 sB = *(const f32x4*)(s4p + (2 * k2 + 1) * 16 + h * 4);
        f32x4 rA = *(const f32x4*)(r4p + (2 * k2) * 16 + h * 4);
        f32x4 rB = *(const f32x4*)(r4p + (2 * k2 + 1) * 16 + h * 4);
        f32x4 a0 = acc[2 * k2], a1 = acc[2 * k2 + 1];
        union { unsigned u[4]; bf16x8 v; } t2;
        t2.u[0] = pk2(fmaxf(a0[0] + sA[0] + rA[0], 0.f), fmaxf(a0[1] + sA[1] + rA[1], 0.f));
        t2.u[1] = pk2(fmaxf(a0[2] + sA[2] + rA[2], 0.f), fmaxf(a0[3] + sA[3] + rA[3], 0.f));
        t2.u[2] = pk2(fmaxf(a1[0] + sB[0] + rB[0], 0.f), fmaxf(a1[1] + sB[1] + rB[1], 0.f));
        t2.u[3] = pk2(fmaxf(a1[2] + sB[2] + rB[2], 0.f), fmaxf(a1[3] + sB[3] + rB[3], 0.f));
        ef[k2] = t2.v;
      }
    }
    // stage 3: e2_hat = u @ w4b   (b4b folded into c4)
#pragma unroll
    for (int kt = 0; kt < 4; kt++)
#pragma unroll
      for (int ft = 0; ft < 8; ft++)
        acc[ft] = mf(wB[kt * 8 + ft], ef[kt], kt == 0 ? Z : acc[ft]);
#pragma unroll
    for (int k2 = 0; k2 < 4; k2++) {
      f32x4 a0 = acc[2 * k2], a1 = acc[2 * k2 + 1];
      union { unsigned u[4]; bf16x8 v; } t2;
      t2.u[0] = pk2(a0[0], a0[1]); t2.u[1] = pk2(a0[2], a0[3]);
      t2.u[2] = pk2(a1[0], a1[1]); t2.u[3] = pk2(a1[2], a1[3]);
      ef[k2] = t2.v;
    }
    // stage 4: out = e2@wout + c4  (wout unpinned: 4 L1-hot loads per tile)
    f32x4 a4 = Z;
#pragma unroll
    for (int kt = 0; kt < 4; kt++) {
      bf16x8 wo = ldfrag(pk + 336 * 512, kt, l);
      a4 = mf(wo, ef[kt], a4);
    }
    if (jj < 63) {
      f32x4 c4v = *(const f32x4*)(c4 + h * 4);
      f32x4 o;
      o[0] = a4[0] + c4v[0]; o[1] = a4[1] + c4v[1];
      o[2] = a4[2] + c4v[2]; o[3] = a4[3] + c4v[3];
      *reinterpret_cast<f32x4*>(out + (b * NE + i * 63 + jj) * 16 + h * 4) = o;
    }
  }
}

extern "C" void kernel_launch(void* const* d_in, const int* in_sizes, int n_in,
                              void* d_out, int out_size, void* d_ws, size_t ws_size,
                              hipStream_t stream) {
  const float* x    = (const float*)d_in[0];
  // d_in[1]=rel_rec, d_in[2]=rel_send: one-hot fully-connected, hardcoded.
  const float* w1a  = (const float*)d_in[3];
  const float* b1a  = (const float*)d_in[4];
  const float* w1b  = (const float*)d_in[5];
  const float* b1b  = (const float*)d_in[6];
  const float* w2a  = (const float*)d_in[7];
  const float* b2a  = (const float*)d_in[8];
  const float* w2b  = (const float*)d_in[9];
  const float* b2b  = (const float*)d_in[10];
  const float* w3a  = (const float*)d_in[11];
  const float* b3a  = (const float*)d_in[12];
  const float* w3b  = (const float*)d_in[13];
  const float* b3b  = (const float*)d_in[14];
  const float* w4a  = (const float*)d_in[15];
  const float* b4a  = (const float*)d_in[16];
  const float* w4b  = (const float*)d_in[17];
  const float* b4b  = (const float*)d_in[18];
  const float* wout = (const float*)d_in[19];
  const float* bout = (const float*)d_in[20];
  float* out = (float*)d_out;

  float* sproj = (float*)d_ws;
  float* rproj = sproj + 524288;
  float* s4    = rproj + 524288;
  float* r4    = s4 + 524288;
  u16* pkw     = (u16*)(r4 + 524288);   // 340 frags * 512 u16
  float* c2    = (float*)(pkw + 174080);
  float* c4    = c2 + 128;

  prepack_kernel<<<dim3(32, 13), 64, 0, stream>>>(
      w1a, w1b, w2a, w2b, w3a, w3b, w4a, w4b, wout, b2b, b4b, bout, pkw, c2, c4);
  node_kernel<<<256, 64, 0, stream>>>(x, pkw, b1a, b1b, b2a, sproj, rproj);
  agg_kernel<<<256, 256, 0, stream>>>(sproj, rproj, pkw, b2b, b3a, b3b, b4a, c2, s4, r4);
  edge_kernel<<<1024, 64, 0, stream>>>(sproj, rproj, s4, r4, pkw, c4, out);
}